// Round 14
// baseline (120.779 us; speedup 1.0000x reference)
//
#include <hip/hip_runtime.h>
#include <hip/hip_bf16.h>

#define D_MODEL 768
#define S_LEN   2048
#define BATCH   2
#define NHEAD   12
#define DH      64
#define NTOK    (BATCH * S_LEN)   // 4096
#define NBH     (BATCH * NHEAD)   // 24

typedef __attribute__((ext_vector_type(8))) short bf16x8;   // 8 bf16 in 4 VGPRs
typedef __attribute__((ext_vector_type(4))) float f32x4;

__device__ inline unsigned short f2bf(float f) {
    union { float f; unsigned u; } v; v.f = f;
    unsigned u = v.u;
    u += 0x7fffu + ((u >> 16) & 1u);
    return (unsigned short)(u >> 16);
}

__device__ inline unsigned pack_bf2(float a, float b) {
    union { __hip_bfloat162 h2; unsigned u; } cv;
    cv.h2 = __float22bfloat162_rn(make_float2(a, b));   // v_cvt_pk_bf16_f32
    return cv.u;
}

__device__ inline float bf2f(unsigned short u) {
    union { unsigned u; float f; } c; c.u = ((unsigned)u) << 16; return c.f;
}

// async global->LDS, 16B per lane. LDS dest is wave-uniform base (+lane*16 by HW).
__device__ inline void stage16(const void* g, void* l) {
    __builtin_amdgcn_global_load_lds(
        (const __attribute__((address_space(1))) unsigned*)g,
        (__attribute__((address_space(3))) unsigned*)l, 16, 0, 0);
}

// ---------------------------------------------------------------------------
// Kernel 1: fp32 -> bf16 conversion of X and the 4 weight matrices
// ---------------------------------------------------------------------------
__global__ __launch_bounds__(256) void convert_kernel(
    const float* __restrict__ Q,
    const float* __restrict__ Wq, const float* __restrict__ Wk,
    const float* __restrict__ Wv, const float* __restrict__ Wo,
    unsigned short* __restrict__ Xb,
    unsigned short* __restrict__ Wqb, unsigned short* __restrict__ Wkb,
    unsigned short* __restrict__ Wvb, unsigned short* __restrict__ Wob)
{
    const int XV = NTOK * D_MODEL / 4;
    const int WV = D_MODEL * D_MODEL / 4;
    int idx = blockIdx.x * 256 + threadIdx.x;
    if (idx >= XV + 4 * WV) return;

    const float* src; unsigned short* dst; int off;
    if (idx < XV) { src = Q; dst = Xb; off = idx; }
    else {
        int i2 = idx - XV;
        int seg = i2 / WV; off = i2 - seg * WV;
        if      (seg == 0) { src = Wq; dst = Wqb; }
        else if (seg == 1) { src = Wk; dst = Wkb; }
        else if (seg == 2) { src = Wv; dst = Wvb; }
        else               { src = Wo; dst = Wob; }
    }
    float4 v = reinterpret_cast<const float4*>(src)[off];
    uint2 o;
    o.x = pack_bf2(v.x, v.y);
    o.y = pack_bf2(v.z, v.w);
    reinterpret_cast<uint2*>(dst)[off] = o;
}

// ===========================================================================
// Staged GEMM pieces, XOR-swizzled LDS via pre-swizzled global source.
// ===========================================================================
#define STAGE_TILE(glob, rowstrideB, row0, k0, ldsbase, nIss)                 \
    _Pragma("unroll")                                                          \
    for (int i = 0; i < (nIss); ++i) {                                         \
        int L = i * 4096 + wv * 1024 + lane * 16;                              \
        int row = L >> 7;                                                      \
        int colb = (L & 127) ^ ((row & 7) << 4);                               \
        stage16((const char*)(glob) + (size_t)((row0) + row) * (rowstrideB)    \
                    + ((k0) << 1) + colb,                                      \
                (char*)(ldsbase) + i * 4096 + wv * 1024);                      \
    }

// ---------------------------------------------------------------------------
// Kernel 2: fused QKV projection, 128x128 tile.  B = [Wq;Wk;Wv] (N=2304).
// XCD swizzle: the 4-row-tile group sharing an X panel co-locates per XCD.
// ---------------------------------------------------------------------------
__global__ __launch_bounds__(256) void qkv_gemm_kernel(
    const unsigned short* __restrict__ Xb,
    const unsigned short* __restrict__ Wall,   // [2304][768]
    const float* __restrict__ bq, const float* __restrict__ bk,
    const float* __restrict__ bv,
    unsigned short* __restrict__ qb, unsigned short* __restrict__ kb,
    unsigned short* __restrict__ vtb)
{
    const int lane = threadIdx.x & 63;
    const int wv   = threadIdx.x >> 6;
    const int lr   = lane & 15;
    const int lg   = lane >> 4;
    const int wr   = wv >> 1;          // 2x2 wave grid
    const int wc   = wv & 1;

    // XCD-aware remap: 576 = 8 xcd * 4 ytiles * 18 xtiles
    const int flat = blockIdx.x + 18 * blockIdx.y;
    const int xcd  = flat & 7;
    const int j    = flat >> 3;        // [0,72)
    const int ybt  = xcd * 4 + j / 18; // row tile [0,32)
    const int xbt  = j % 18;           // col tile [0,18)
    const int row0g = ybt * 128;
    const int col0g = xbt * 128;

    __shared__ __align__(16) unsigned short At[2][128 * 64];   // 16 KB each
    __shared__ __align__(16) unsigned short Bt[2][128 * 64];

    f32x4 acc[4][4] = {};

    STAGE_TILE(Xb,   1536, row0g, 0, At[0], 4);
    STAGE_TILE(Wall, 1536, col0g, 0, Bt[0], 4);
    __syncthreads();

    for (int s = 0; s < 12; ++s) {
        int cur = s & 1;
        if (s < 11) {
            STAGE_TILE(Xb,   1536, row0g, (s + 1) * 64, At[cur ^ 1], 4);
            STAGE_TILE(Wall, 1536, col0g, (s + 1) * 64, Bt[cur ^ 1], 4);
        }
        bf16x8 a[4][2], b[4][2];
#pragma unroll
        for (int mm = 0; mm < 4; ++mm) {
            int row = wr * 64 + mm * 16 + lr, sw = (row & 7) << 4;
#pragma unroll
            for (int ks = 0; ks < 2; ++ks)
                a[mm][ks] = *reinterpret_cast<const bf16x8*>(
                    (const char*)At[cur] + row * 128 + ((ks * 64 + lg * 16) ^ sw));
        }
#pragma unroll
        for (int n = 0; n < 4; ++n) {
            int row = wc * 64 + n * 16 + lr, sw = (row & 7) << 4;
#pragma unroll
            for (int ks = 0; ks < 2; ++ks)
                b[n][ks] = *reinterpret_cast<const bf16x8*>(
                    (const char*)Bt[cur] + row * 128 + ((ks * 64 + lg * 16) ^ sw));
        }
#pragma unroll
        for (int ks = 0; ks < 2; ++ks)
#pragma unroll
            for (int mm = 0; mm < 4; ++mm)
#pragma unroll
                for (int n = 0; n < 4; ++n)
                    acc[mm][n] = __builtin_amdgcn_mfma_f32_16x16x32_bf16(
                        a[mm][ks], b[n][ks], acc[mm][n], 0, 0, 0);
        __syncthreads();
    }

    const int which   = xbt / 6;                  // 2304/128=18, 6 per output
    const int colbase = (xbt % 6) * 128;
    const float* bias = (which == 0) ? bq : (which == 1) ? bk : bv;
#pragma unroll
    for (int mm = 0; mm < 4; ++mm) {
#pragma unroll
        for (int n = 0; n < 4; ++n) {
            int col = colbase + wc * 64 + n * 16 + lr;
            float bval = bias[col];
            int h = col >> 6, d = col & 63;
            int rowg = row0g + wr * 64 + mm * 16 + lg * 4;
            int bb = rowg >> 11, s0 = rowg & 2047;
            if (which == 2) {
                uint2 w;
                w.x = pack_bf2(acc[mm][n][0] + bval, acc[mm][n][1] + bval);
                w.y = pack_bf2(acc[mm][n][2] + bval, acc[mm][n][3] + bval);
                *reinterpret_cast<uint2*>(
                    vtb + ((size_t)(bb * NHEAD + h) * DH + d) * S_LEN + s0) = w;
            } else {
                unsigned short* dst = (which == 0) ? qb : kb;
#pragma unroll
                for (int r = 0; r < 4; ++r)
                    dst[((size_t)(bb * NHEAD + h) * S_LEN + s0 + r) * DH + d] =
                        f2bf(acc[mm][n][r] + bval);
            }
        }
    }
}

// ===========================================================================
// Kernel 3: attention (r10 proven structure).  8 waves x 16 q-rows; K,V
// triple-buffered LDS via global_load_lds (only vmem in loop -> exact counted
// vmcnt(2)), depth-2 prefetch, raw barriers.  XCD swizzle co-locates the 16
// q-tiles of one (bh,ks) group per XCD.
// ===========================================================================
#define AC1(BUF, DOSTAGE, VM)                                                  \
    {                                                                          \
        if (DOSTAGE) {                                                         \
            stage16(kg, sdK[((BUF) + 2) % 3]); kg += 8192;                     \
            stage16(vg, sdV[((BUF) + 2) % 3]); vg += 128;                      \
        }                                                                      \
        f32x4 s[4] = {};                                                       \
        __builtin_amdgcn_s_setprio(1);                                         \
        _Pragma("unroll")                                                      \
        for (int kt = 0; kt < 4; ++kt) {                                       \
            bf16x8 ak0 = *(const bf16x8*)(rdK[BUF] + kt * 2048);               \
            bf16x8 ak1 = *(const bf16x8*)(rdK[BUF] + kt * 2048 + oD);          \
            s[kt] = __builtin_amdgcn_mfma_f32_16x16x32_bf16(ak0, bq0, s[kt], 0, 0, 0); \
            s[kt] = __builtin_amdgcn_mfma_f32_16x16x32_bf16(ak1, bq1, s[kt], 0, 0, 0); \
        }                                                                      \
        __builtin_amdgcn_s_setprio(0);                                         \
        bf16x8 av0[4], av1[4];                                                 \
        _Pragma("unroll")                                                      \
        for (int t = 0; t < 4; ++t) {                                          \
            av0[t] = *(const bf16x8*)(rdV[BUF] + t * 2048);                    \
            av1[t] = *(const bf16x8*)(rdV[BUF] + t * 2048 + oD);               \
        }                                                                      \
        float g0 = fmaxf(fmaxf(s[0][0], s[0][1]), s[0][2]);                    \
        float g1 = fmaxf(fmaxf(s[0][3], s[1][0]), s[1][1]);                    \
        float g2 = fmaxf(fmaxf(s[1][2], s[1][3]), s[2][0]);                    \
        float g3 = fmaxf(fmaxf(s[2][1], s[2][2]), s[2][3]);                    \
        float g4 = fmaxf(fmaxf(s[3][0], s[3][1]), s[3][2]);                    \
        float mx = fmaxf(fmaxf(fmaxf(g0, g1), g2), fmaxf(fmaxf(g3, g4), s[3][3])); \
        if (__any(mx * SC > m + 8.0f)) {                                       \
            float mg = mx * SC;                                                \
            mg = fmaxf(mg, __shfl_xor(mg, 16));                                \
            mg = fmaxf(mg, __shfl_xor(mg, 32));                                \
            float mn = fmaxf(m, mg);                                           \
            float sf = __builtin_amdgcn_exp2f(m - mn);                         \
            m = mn; l *= sf;                                                   \
            _Pragma("unroll")                                                  \
            for (int t = 0; t < 4; ++t) acc[t] *= sf;                          \
        }                                                                      \
        float p[16];                                                           \
        _Pragma("unroll")                                                      \
        for (int kt = 0; kt < 4; ++kt)                                         \
            _Pragma("unroll")                                                  \
            for (int r = 0; r < 4; ++r)                                        \
                p[kt * 4 + r] = __builtin_amdgcn_exp2f(fmaf(s[kt][r], SC, -m)); \
        float sum = ((p[0] + p[1]) + (p[2] + p[3])) + ((p[4] + p[5]) + (p[6] + p[7])); \
        sum += ((p[8] + p[9]) + (p[10] + p[11])) + ((p[12] + p[13]) + (p[14] + p[15])); \
        l += sum;                                                              \
        _Pragma("unroll")                                                      \
        for (int kt = 0; kt < 4; ++kt) {                                       \
            uint2 w;                                                           \
            w.x = pack_bf2(p[kt * 4 + 0], p[kt * 4 + 1]);                      \
            w.y = pack_bf2(p[kt * 4 + 2], p[kt * 4 + 3]);                      \
            *(uint2*)(plw + kt * 32 + lg * 8) = w;                             \
        }                                                                      \
        union { bf16x8 v; uint2 u[2]; } bp0, bp1;                              \
        bp0.u[0] = *(const uint2*)(plr);                                       \
        bp0.u[1] = *(const uint2*)(plr + 8);                                   \
        bp1.u[0] = *(const uint2*)(plr + 64);                                  \
        bp1.u[1] = *(const uint2*)(plr + 72);                                  \
        __builtin_amdgcn_s_setprio(1);                                         \
        _Pragma("unroll")                                                      \
        for (int t = 0; t < 4; ++t) {                                          \
            acc[t] = __builtin_amdgcn_mfma_f32_16x16x32_bf16(av0[t], bp0.v, acc[t], 0, 0, 0); \
            acc[t] = __builtin_amdgcn_mfma_f32_16x16x32_bf16(av1[t], bp1.v, acc[t], 0, 0, 0); \
        }                                                                      \
        __builtin_amdgcn_s_setprio(0);                                         \
        if ((VM) == 2) {                                                       \
            asm volatile("s_waitcnt vmcnt(2)" ::: "memory");                   \
            __builtin_amdgcn_s_barrier();                                      \
        } else if ((VM) == 0) {                                                \
            asm volatile("s_waitcnt vmcnt(0)" ::: "memory");                   \
            __builtin_amdgcn_s_barrier();                                      \
        }                                                                      \
    }

template<int KS>
__global__ __launch_bounds__(512) void attn_kernel(
    const unsigned short* __restrict__ qb, const unsigned short* __restrict__ kb,
    const unsigned short* __restrict__ vtb,
    unsigned short* __restrict__ attnb,
    unsigned short* __restrict__ Opart,    // [KS][NBH][2048][64] bf16 (KS==2)
    float2* __restrict__ mlbuf)            // [KS][NBH][2048]        (KS==2)
{
    const int lane = threadIdx.x & 63;
    const int wv   = threadIdx.x >> 6;
    const int lr   = lane & 15;
    const int lg   = lane >> 4;

    int flat = blockIdx.x + 16 * blockIdx.y + ((KS == 2) ? 384 * blockIdx.z : 0);
    const int xcd = flat & 7;
    const int j   = flat >> 3;
    const int g   = xcd * ((KS == 2) ? 6 : 3) + (j >> 4);
    const int qt  = j & 15;
    const int bh  = (KS == 2) ? (g % 24) : g;
    const int ks  = (KS == 2) ? (g / 24) : 0;
    const int h   = bh % NHEAD, bb = bh / NHEAD;
    const int q0  = qt * 128 + wv * 16;

    __shared__ __align__(16) unsigned short Kt[3][4096];
    __shared__ __align__(16) unsigned short Vt[3][4096];
    __shared__ __align__(16) unsigned short PL[8][16][68];

    const char* kbase = (const char*)(kb  + (size_t)bh * S_LEN * DH)
                        + (size_t)ks * (S_LEN / KS) * 128;
    const char* vbase = (const char*)(vtb + (size_t)bh * DH * S_LEN)
                        + (size_t)ks * (S_LEN / KS) * 2;
    const unsigned short* qptr = qb + ((size_t)bh * S_LEN + q0) * DH;

    bf16x8 bq0 = *reinterpret_cast<const bf16x8*>(qptr + (size_t)lr * DH + lg * 8);
    bf16x8 bq1 = *reinterpret_cast<const bf16x8*>(qptr + (size_t)lr * DH + 32 + lg * 8);

    const int swr = (lr & 7) << 4;
    const int o0  = (lg * 16) ^ swr;
    const int oD  = (o0 ^ 64) - o0;
    const int L1  = wv * 1024 + lane * 16;
    const int r1  = L1 >> 7;
    const int cb1 = (L1 & 127) ^ ((r1 & 7) << 4);

    const char* kg = kbase + (size_t)r1 * 128 + cb1;
    const char* vg = vbase + (size_t)r1 * 4096 + cb1;
    char* sdK[3] = { (char*)Kt[0] + wv * 1024, (char*)Kt[1] + wv * 1024,
                     (char*)Kt[2] + wv * 1024 };
    char* sdV[3] = { (char*)Vt[0] + wv * 1024, (char*)Vt[1] + wv * 1024,
                     (char*)Vt[2] + wv * 1024 };
    const char* rdK[3] = {
        (const char*)Kt[0] + lr * 128 + o0,
        (const char*)Kt[1] + lr * 128 + o0,
        (const char*)Kt[2] + lr * 128 + o0 };
    const char* rdV[3] = {
        (const char*)Vt[0] + lr * 128 + o0,
        (const char*)Vt[1] + lr * 128 + o0,
        (const char*)Vt[2] + lr * 128 + o0 };
    char* plw = (char*)PL + wv * 2176 + lr * 136;
    const char* plr = plw + lg * 16;

    float m = -1e30f, l = 0.f;
    f32x4 acc[4] = {};
    const float SC = 0.125f * 1.44269504088896f;

    stage16(kg, sdK[0]); kg += 8192;
    stage16(vg, sdV[0]); vg += 128;
    stage16(kg, sdK[1]); kg += 8192;
    stage16(vg, sdV[1]); vg += 128;
    asm volatile("s_waitcnt vmcnt(2)" ::: "memory");
    __builtin_amdgcn_s_barrier();

    if constexpr (KS == 2) {
        for (int it = 0; it < 4; ++it) {
            AC1(0, 1, 2); AC1(1, 1, 2); AC1(2, 1, 2);
        }
        AC1(0, 1, 2); AC1(1, 1, 2); AC1(2, 0, 0); AC1(0, 0, -1);
    } else {
        for (int it = 0; it < 10; ++it) {
            AC1(0, 1, 2); AC1(1, 1, 2); AC1(2, 1, 2);
        }
        AC1(0, 0, 0); AC1(1, 0, -1);
    }

    l += __shfl_xor(l, 16);
    l += __shfl_xor(l, 32);

    if constexpr (KS == 1) {
        float rl = 1.0f / l;
        size_t rowbase = ((size_t)(bb * S_LEN + q0 + lr)) * D_MODEL + h * DH;
#pragma unroll
        for (int t = 0; t < 4; ++t) {
            *reinterpret_cast<unsigned*>(attnb + rowbase + t * 16 + lg * 4) =
                pack_bf2(acc[t][0] * rl, acc[t][1] * rl);
            *reinterpret_cast<unsigned*>(attnb + rowbase + t * 16 + lg * 4 + 2) =
                pack_bf2(acc[t][2] * rl, acc[t][3] * rl);
        }
    } else {
        size_t base = ((size_t)(ks * NBH + bh) * S_LEN + q0 + lr) * 64;
#pragma unroll
        for (int t = 0; t < 4; ++t) {
            *reinterpret_cast<unsigned*>(Opart + base + t * 16 + lg * 4) =
                pack_bf2(acc[t][0], acc[t][1]);
            *reinterpret_cast<unsigned*>(Opart + base + t * 16 + lg * 4 + 2) =
                pack_bf2(acc[t][2], acc[t][3]);
        }
        if (lg == 0)
            mlbuf[(size_t)(ks * NBH + bh) * S_LEN + q0 + lr] = make_float2(m, l);
    }
}

// ---------------------------------------------------------------------------
// Kernel 3b: combine the KS splits into attnb (bf16 [token][768]).
// ---------------------------------------------------------------------------
template<int KS>
__global__ __launch_bounds__(256) void combine_kernel(
    const unsigned short* __restrict__ Opart,
    const float2* __restrict__ mlbuf,
    unsigned short* __restrict__ attnb)
{
    int idx = blockIdx.x * 256 + threadIdx.x;      // 786432 total
    int d4  = idx & 15;
    int h   = (idx >> 4) % 12;
    int tok = idx / 192;
    int bb  = tok >> 11, s = tok & 2047;
    size_t qoff = (size_t)(bb * NHEAD + h) * S_LEN + s;

    float2 ml[KS];
    float M = -1e30f;
#pragma unroll
    for (int k = 0; k < KS; ++k) {
        ml[k] = mlbuf[(size_t)k * NBH * S_LEN + qoff];
        M = fmaxf(M, ml[k].x);
    }
    float wgt[KS], denom = 0.f;
#pragma unroll
    for (int k = 0; k < KS; ++k) {
        wgt[k] = __builtin_amdgcn_exp2f(ml[k].x - M);
        denom += wgt[k] * ml[k].y;
    }
    float ri = 1.0f / denom;
    float o0 = 0.f, o1 = 0.f, o2 = 0.f, o3 = 0.f;
    size_t ob = qoff * 64 + d4 * 4;
#pragma unroll
    for (int k = 0; k < KS; ++k) {
        ushort4 a = *reinterpret_cast<const ushort4*>(
            Opart + (size_t)k * NBH * S_LEN * 64 + ob);
        float w = wgt[k] * ri;
        o0 += bf2f(a.x) * w; o1 += bf2f(a.y) * w;
        o2 += bf2f(a.z) * w; o3 += bf2f(a.w) * w;
    }
    uint2 w;
    w.x = pack_bf2(o0, o1);
    w.y = pack_bf2(o2, o3);
    *reinterpret_cast<uint2*>(attnb + (size_t)tok * D_MODEL + h * 64 + d4 * 4) = w;
}

// ---------------------------------------------------------------------------
// Kernel 4: output projection, 128x128 tile (same core as qkv).
// grid (6,32) -> 192 blocks = 8 xcd * 4 ytiles * 6 xtiles.
// ---------------------------------------------------------------------------
__global__ __launch_bounds__(256) void oproj_kernel(
    const unsigned short* __restrict__ attnb, const unsigned short* __restrict__ Wob,
    const float* __restrict__ bo, const float* __restrict__ Qres,
    float* __restrict__ Y)
{
    const int lane = threadIdx.x & 63;
    const int wv   = threadIdx.x >> 6;
    const int lr   = lane & 15;
    const int lg   = lane >> 4;
    const int wr   = wv >> 1;
    const int wc   = wv & 1;

    const int flat = blockIdx.x + 6 * blockIdx.y;
    const int xcd  = flat & 7;
    const int j    = flat >> 3;        // [0,24)
    const int ybt  = xcd * 4 + j / 6;  // [0,32)
    const int xbt  = j % 6;            // [0,6)
    const int row0g = ybt * 128;
    const int col0g = xbt * 128;

    __shared__ __align__(16) unsigned short At[2][128 * 64];
    __shared__ __align__(16) unsigned short Bt[2][128 * 64];

    f32x4 acc[4][4] = {};

    STAGE_TILE(attnb, 1536, row0g, 0, At[0], 4);
    STAGE_TILE(Wob,   1536, col0g, 0, Bt[0], 4);
    __syncthreads();

    for (int s = 0; s < 12; ++s) {
        int cur = s & 1;
        if (s < 11) {
            STAGE_TILE(attnb, 1536, row0g, (s + 1) * 64, At[cur ^ 1], 4);
            STAGE_TILE(Wob,   1536, col0g, (s + 1) * 64, Bt[cur ^ 1], 4);
        }
        bf16x8 a[4][2], b[4][2];
#pragma unroll
        for (int mm = 0; mm < 4; ++mm) {
            int row = wr * 64 + mm * 16 + lr, sw = (row & 7) << 4;
#pragma unroll
            for (int ks = 0; ks < 2; ++ks)
                a[mm][ks] = *reinterpret_cast<const bf16x8*>(
                    (const char*)At[cur] + row * 128 + ((ks * 64 + lg * 16) ^ sw));
        }
#pragma unroll
        for (int n = 0; n < 4; ++n) {
            int row = wc * 64 + n * 16 + lr, sw = (row & 7) << 4;
#pragma unroll
            for (int ks = 0; ks < 2; ++ks)
                b[n][ks] = *reinterpret_cast<const bf16x8*>(
                    (const char*)Bt[cur] + row * 128 + ((ks * 64 + lg * 16) ^ sw));
        }
#pragma unroll
        for (int ks = 0; ks < 2; ++ks)
#pragma unroll
            for (int mm = 0; mm < 4; ++mm)
#pragma unroll
                for (int n = 0; n < 4; ++n)
                    acc[mm][n] = __builtin_amdgcn_mfma_f32_16x16x32_bf16(
                        a[mm][ks], b[n][ks], acc[mm][n], 0, 0, 0);
        __syncthreads();
    }

#pragma unroll
    for (int mm = 0; mm < 4; ++mm)
#pragma unroll
        for (int n = 0; n < 4; ++n) {
            int col = col0g + wc * 64 + n * 16 + lr;
            float bval = bo[col];
#pragma unroll
            for (int r = 0; r < 4; ++r) {
                int row = row0g + wr * 64 + mm * 16 + lg * 4 + r;
                size_t off = (size_t)row * D_MODEL + col;
                Y[off] = acc[mm][n][r] + bval + Qres[off];
            }
        }
}

// ---------------------------------------------------------------------------
// Kernel 5: LayerNorm per row.
// ---------------------------------------------------------------------------
__global__ __launch_bounds__(256) void ln_kernel(
    const float* __restrict__ Y,
    const float* __restrict__ gamma, const float* __restrict__ beta,
    float* __restrict__ out)
{
    const int lane = threadIdx.x & 63;
    const int row  = blockIdx.x * 4 + (threadIdx.x >> 6);
    const float4* yr = reinterpret_cast<const float4*>(Y + (size_t)row * D_MODEL);

    float4 v[3];
    float sum = 0.f, ss = 0.f;
#pragma unroll
    for (int j = 0; j < 3; ++j) {
        v[j] = yr[lane + 64 * j];
        sum += v[j].x + v[j].y + v[j].z + v[j].w;
        ss  += v[j].x * v[j].x + v[j].y * v[j].y + v[j].z * v[j].z + v[j].w * v[j].w;
    }
#pragma unroll
    for (int msk = 1; msk < 64; msk <<= 1) {
        sum += __shfl_xor(sum, msk);
        ss  += __shfl_xor(ss,  msk);
    }
    float mu  = sum * (1.f / 768.f);
    float var = ss * (1.f / 768.f) - mu * mu;
    float is  = rsqrtf(var + 1e-5f);

    const float4* g4 = reinterpret_cast<const float4*>(gamma);
    const float4* b4 = reinterpret_cast<const float4*>(beta);
    float4* o4 = reinterpret_cast<float4*>(out + (size_t)row * D_MODEL);
#pragma unroll
    for (int j = 0; j < 3; ++j) {
        float4 g = g4[lane + 64 * j], b = b4[lane + 64 * j], r;
        r.x = (v[j].x - mu) * is * g.x + b.x;
        r.y = (v[j].y - mu) * is * g.y + b.y;
        r.z = (v[j].z - mu) * is * g.z + b.z;
        r.w = (v[j].w - mu) * is * g.w + b.w;
        o4[lane + 64 * j] = r;
    }
}

// ---------------------------------------------------------------------------
extern "C" void kernel_launch(void* const* d_in, const int* in_sizes, int n_in,
                              void* d_out, int out_size, void* d_ws, size_t ws_size,
                              hipStream_t stream)
{
    const float* Q     = (const float*)d_in[0];
    const float* Wq    = (const float*)d_in[1];
    const float* bq    = (const float*)d_in[2];
    const float* Wk    = (const float*)d_in[3];
    const float* bk    = (const float*)d_in[4];
    const float* Wv    = (const float*)d_in[5];
    const float* bv    = (const float*)d_in[6];
    const float* Wo    = (const float*)d_in[7];
    const float* bo    = (const float*)d_in[8];
    const float* gamma = (const float*)d_in[9];
    const float* beta  = (const float*)d_in[10];
    float* out = (float*)d_out;

    char* ws = (char*)d_ws;
    unsigned short* Xb    = (unsigned short*)(ws + 0);
    unsigned short* Wqb   = (unsigned short*)(ws + 6291456);    // Wq,Wk,Wv contiguous
    unsigned short* Wkb   = (unsigned short*)(ws + 7471104);
    unsigned short* Wvb   = (unsigned short*)(ws + 8650752);
    unsigned short* Wob   = (unsigned short*)(ws + 9830400);
    unsigned short* qb    = (unsigned short*)(ws + 11010048);
    unsigned short* kb    = (unsigned short*)(ws + 17301504);
    unsigned short* vtb   = (unsigned short*)(ws + 23592960);
    unsigned short* attnb = (unsigned short*)(ws + 29884416);
    float*          Yf    = (float*)        (ws + 36175872);    // 12.6 MB
    unsigned short* Opartb = (unsigned short*)(ws + 36175872);  // overlay
    float2*         mlbuf2 = (float2*)       (ws + 61341696);   // end 62128128

    convert_kernel<<<5376, 256, 0, stream>>>(Q, Wq, Wk, Wv, Wo, Xb, Wqb, Wkb, Wvb, Wob);
    qkv_gemm_kernel<<<dim3(18, 32), 256, 0, stream>>>(Xb, Wqb, bq, bk, bv, qb, kb, vtb);
    if (ws_size >= 62128128ull) {
        attn_kernel<2><<<dim3(16, 24, 2), 512, 0, stream>>>(qb, kb, vtb, attnb,
                                                            Opartb, mlbuf2);
        combine_kernel<2><<<3072, 256, 0, stream>>>(Opartb, mlbuf2, attnb);
    } else {
        attn_kernel<1><<<dim3(16, 24), 512, 0, stream>>>(qb, kb, vtb, attnb,
                                                         Opartb, mlbuf2);
    }
    oproj_kernel<<<dim3(6, 32), 256, 0, stream>>>(attnb, Wob, bo, Q, Yf);
    ln_kernel<<<1024, 256, 0, stream>>>(Yf, gamma, beta, out);
}

// Round 15
// 110.598 us; speedup vs baseline: 1.0921x; 1.0921x over previous
//
#include <hip/hip_runtime.h>
#include <hip/hip_bf16.h>

#define D_MODEL 768
#define S_LEN   2048
#define BATCH   2
#define NHEAD   12
#define DH      64
#define NTOK    (BATCH * S_LEN)   // 4096
#define NBH     (BATCH * NHEAD)   // 24

typedef __attribute__((ext_vector_type(8))) short bf16x8;   // 8 bf16 in 4 VGPRs
typedef __attribute__((ext_vector_type(4))) float f32x4;

__device__ inline unsigned short f2bf(float f) {
    union { float f; unsigned u; } v; v.f = f;
    unsigned u = v.u;
    u += 0x7fffu + ((u >> 16) & 1u);
    return (unsigned short)(u >> 16);
}

__device__ inline unsigned pack_bf2(float a, float b) {
    union { __hip_bfloat162 h2; unsigned u; } cv;
    cv.h2 = __float22bfloat162_rn(make_float2(a, b));   // v_cvt_pk_bf16_f32
    return cv.u;
}

__device__ inline float bf2f(unsigned short u) {
    union { unsigned u; float f; } c; c.u = ((unsigned)u) << 16; return c.f;
}

// async global->LDS, 16B per lane. LDS dest is wave-uniform base (+lane*16 by HW).
__device__ inline void stage16(const void* g, void* l) {
    __builtin_amdgcn_global_load_lds(
        (const __attribute__((address_space(1))) unsigned*)g,
        (__attribute__((address_space(3))) unsigned*)l, 16, 0, 0);
}

// ---------------------------------------------------------------------------
// Kernel 1: fp32 -> bf16 conversion of X and the 4 weight matrices
// ---------------------------------------------------------------------------
__global__ __launch_bounds__(256) void convert_kernel(
    const float* __restrict__ Q,
    const float* __restrict__ Wq, const float* __restrict__ Wk,
    const float* __restrict__ Wv, const float* __restrict__ Wo,
    unsigned short* __restrict__ Xb,
    unsigned short* __restrict__ Wqb, unsigned short* __restrict__ Wkb,
    unsigned short* __restrict__ Wvb, unsigned short* __restrict__ Wob)
{
    const int XV = NTOK * D_MODEL / 4;
    const int WV = D_MODEL * D_MODEL / 4;
    int idx = blockIdx.x * 256 + threadIdx.x;
    if (idx >= XV + 4 * WV) return;

    const float* src; unsigned short* dst; int off;
    if (idx < XV) { src = Q; dst = Xb; off = idx; }
    else {
        int i2 = idx - XV;
        int seg = i2 / WV; off = i2 - seg * WV;
        if      (seg == 0) { src = Wq; dst = Wqb; }
        else if (seg == 1) { src = Wk; dst = Wkb; }
        else if (seg == 2) { src = Wv; dst = Wvb; }
        else               { src = Wo; dst = Wob; }
    }
    float4 v = reinterpret_cast<const float4*>(src)[off];
    uint2 o;
    o.x = pack_bf2(v.x, v.y);
    o.y = pack_bf2(v.z, v.w);
    reinterpret_cast<uint2*>(dst)[off] = o;
}

// ===========================================================================
// Staged GEMM pieces, XOR-swizzled LDS via pre-swizzled global source.
// ===========================================================================
#define STAGE_TILE(glob, rowstrideB, row0, k0, ldsbase, nIss)                 \
    _Pragma("unroll")                                                          \
    for (int i = 0; i < (nIss); ++i) {                                         \
        int L = i * 4096 + wv * 1024 + lane * 16;                              \
        int row = L >> 7;                                                      \
        int colb = (L & 127) ^ ((row & 7) << 4);                               \
        stage16((const char*)(glob) + (size_t)((row0) + row) * (rowstrideB)    \
                    + ((k0) << 1) + colb,                                      \
                (char*)(ldsbase) + i * 4096 + wv * 1024);                      \
    }

// ---------------------------------------------------------------------------
// Kernel 2: fused QKV projection, 128x128 tile.  B = [Wq;Wk;Wv] (N=2304).
// XCD swizzle: the 4-row-tile group sharing an X panel co-locates per XCD.
// ---------------------------------------------------------------------------
__global__ __launch_bounds__(256) void qkv_gemm_kernel(
    const unsigned short* __restrict__ Xb,
    const unsigned short* __restrict__ Wall,   // [2304][768]
    const float* __restrict__ bq, const float* __restrict__ bk,
    const float* __restrict__ bv,
    unsigned short* __restrict__ qb, unsigned short* __restrict__ kb,
    unsigned short* __restrict__ vtb)
{
    const int lane = threadIdx.x & 63;
    const int wv   = threadIdx.x >> 6;
    const int lr   = lane & 15;
    const int lg   = lane >> 4;
    const int wr   = wv >> 1;          // 2x2 wave grid
    const int wc   = wv & 1;

    // XCD-aware remap: 576 = 8 xcd * 4 ytiles * 18 xtiles
    const int flat = blockIdx.x + 18 * blockIdx.y;
    const int xcd  = flat & 7;
    const int j    = flat >> 3;        // [0,72)
    const int ybt  = xcd * 4 + j / 18; // row tile [0,32)
    const int xbt  = j % 18;           // col tile [0,18)
    const int row0g = ybt * 128;
    const int col0g = xbt * 128;

    __shared__ __align__(16) unsigned short At[2][128 * 64];   // 16 KB each
    __shared__ __align__(16) unsigned short Bt[2][128 * 64];

    f32x4 acc[4][4] = {};

    STAGE_TILE(Xb,   1536, row0g, 0, At[0], 4);
    STAGE_TILE(Wall, 1536, col0g, 0, Bt[0], 4);
    __syncthreads();

    for (int s = 0; s < 12; ++s) {
        int cur = s & 1;
        if (s < 11) {
            STAGE_TILE(Xb,   1536, row0g, (s + 1) * 64, At[cur ^ 1], 4);
            STAGE_TILE(Wall, 1536, col0g, (s + 1) * 64, Bt[cur ^ 1], 4);
        }
        bf16x8 a[4][2], b[4][2];
#pragma unroll
        for (int mm = 0; mm < 4; ++mm) {
            int row = wr * 64 + mm * 16 + lr, sw = (row & 7) << 4;
#pragma unroll
            for (int ks = 0; ks < 2; ++ks)
                a[mm][ks] = *reinterpret_cast<const bf16x8*>(
                    (const char*)At[cur] + row * 128 + ((ks * 64 + lg * 16) ^ sw));
        }
#pragma unroll
        for (int n = 0; n < 4; ++n) {
            int row = wc * 64 + n * 16 + lr, sw = (row & 7) << 4;
#pragma unroll
            for (int ks = 0; ks < 2; ++ks)
                b[n][ks] = *reinterpret_cast<const bf16x8*>(
                    (const char*)Bt[cur] + row * 128 + ((ks * 64 + lg * 16) ^ sw));
        }
#pragma unroll
        for (int ks = 0; ks < 2; ++ks)
#pragma unroll
            for (int mm = 0; mm < 4; ++mm)
#pragma unroll
                for (int n = 0; n < 4; ++n)
                    acc[mm][n] = __builtin_amdgcn_mfma_f32_16x16x32_bf16(
                        a[mm][ks], b[n][ks], acc[mm][n], 0, 0, 0);
        __syncthreads();
    }

    const int which   = xbt / 6;                  // 2304/128=18, 6 per output
    const int colbase = (xbt % 6) * 128;
    const float* bias = (which == 0) ? bq : (which == 1) ? bk : bv;
#pragma unroll
    for (int mm = 0; mm < 4; ++mm) {
#pragma unroll
        for (int n = 0; n < 4; ++n) {
            int col = colbase + wc * 64 + n * 16 + lr;
            float bval = bias[col];
            int h = col >> 6, d = col & 63;
            int rowg = row0g + wr * 64 + mm * 16 + lg * 4;
            int bb = rowg >> 11, s0 = rowg & 2047;
            if (which == 2) {
                uint2 w;
                w.x = pack_bf2(acc[mm][n][0] + bval, acc[mm][n][1] + bval);
                w.y = pack_bf2(acc[mm][n][2] + bval, acc[mm][n][3] + bval);
                *reinterpret_cast<uint2*>(
                    vtb + ((size_t)(bb * NHEAD + h) * DH + d) * S_LEN + s0) = w;
            } else {
                unsigned short* dst = (which == 0) ? qb : kb;
#pragma unroll
                for (int r = 0; r < 4; ++r)
                    dst[((size_t)(bb * NHEAD + h) * S_LEN + s0 + r) * DH + d] =
                        f2bf(acc[mm][n][r] + bval);
            }
        }
    }
}

// ---------------------------------------------------------------------------
// Kernel 3: attention (r10 structure).  8 waves x 16 q-rows; K,V triple-
// buffered LDS, counted vmcnt(2), depth-2 prefetch.  XCD swizzle: the 16
// q-blocks sharing one (bh,ks) K/V co-locate on one XCD.
// ---------------------------------------------------------------------------
#define AC(BUF, DOSTAGE, VM)                                                   \
    {                                                                          \
        if (DOSTAGE) {                                                         \
            stage16(kg, sdK[((BUF) + 2) % 3]); kg += 8192;                     \
            stage16(vg, sdV[((BUF) + 2) % 3]); vg += 128;                      \
        }                                                                      \
        f32x4 s[4] = {};                                                       \
        __builtin_amdgcn_s_setprio(1);                                         \
        _Pragma("unroll")                                                      \
        for (int kt = 0; kt < 4; ++kt) {                                       \
            bf16x8 ak0 = *(const bf16x8*)(rdK[BUF] + kt * 2048);               \
            bf16x8 ak1 = *(const bf16x8*)(rdK[BUF] + kt * 2048 + oD);          \
            s[kt] = __builtin_amdgcn_mfma_f32_16x16x32_bf16(ak0, bq0, s[kt], 0, 0, 0); \
            s[kt] = __builtin_amdgcn_mfma_f32_16x16x32_bf16(ak1, bq1, s[kt], 0, 0, 0); \
        }                                                                      \
        __builtin_amdgcn_s_setprio(0);                                         \
        bf16x8 av0[4], av1[4];                                                 \
        _Pragma("unroll")                                                      \
        for (int t = 0; t < 4; ++t) {                                          \
            av0[t] = *(const bf16x8*)(rdV[BUF] + t * 2048);                    \
            av1[t] = *(const bf16x8*)(rdV[BUF] + t * 2048 + oD);               \
        }                                                                      \
        float g0 = fmaxf(fmaxf(s[0][0], s[0][1]), s[0][2]);                    \
        float g1 = fmaxf(fmaxf(s[0][3], s[1][0]), s[1][1]);                    \
        float g2 = fmaxf(fmaxf(s[1][2], s[1][3]), s[2][0]);                    \
        float g3 = fmaxf(fmaxf(s[2][1], s[2][2]), s[2][3]);                    \
        float g4 = fmaxf(fmaxf(s[3][0], s[3][1]), s[3][2]);                    \
        float mx = fmaxf(fmaxf(fmaxf(g0, g1), g2), fmaxf(fmaxf(g3, g4), s[3][3])); \
        if (__any(mx * SC > m + 8.0f)) {                                       \
            float mg = mx * SC;                                                \
            mg = fmaxf(mg, __shfl_xor(mg, 16));                                \
            mg = fmaxf(mg, __shfl_xor(mg, 32));                                \
            float mn = fmaxf(m, mg);                                           \
            float sf = __builtin_amdgcn_exp2f(m - mn);                         \
            m = mn; l *= sf;                                                   \
            _Pragma("unroll")                                                  \
            for (int t = 0; t < 4; ++t) acc[t] *= sf;                          \
        }                                                                      \
        float p[16];                                                           \
        _Pragma("unroll")                                                      \
        for (int kt = 0; kt < 4; ++kt)                                         \
            _Pragma("unroll")                                                  \
            for (int r = 0; r < 4; ++r)                                        \
                p[kt * 4 + r] = __builtin_amdgcn_exp2f(fmaf(s[kt][r], SC, -m)); \
        float sum = ((p[0] + p[1]) + (p[2] + p[3])) + ((p[4] + p[5]) + (p[6] + p[7])); \
        sum += ((p[8] + p[9]) + (p[10] + p[11])) + ((p[12] + p[13]) + (p[14] + p[15])); \
        l += sum;                                                              \
        _Pragma("unroll")                                                      \
        for (int kt = 0; kt < 4; ++kt) {                                       \
            uint2 w;                                                           \
            w.x = pack_bf2(p[kt * 4 + 0], p[kt * 4 + 1]);                      \
            w.y = pack_bf2(p[kt * 4 + 2], p[kt * 4 + 3]);                      \
            *(uint2*)(plw + kt * 32 + lg * 8) = w;                             \
        }                                                                      \
        union { bf16x8 v; uint2 u[2]; } bp0, bp1;                              \
        bp0.u[0] = *(const uint2*)(plr);                                       \
        bp0.u[1] = *(const uint2*)(plr + 8);                                   \
        bp1.u[0] = *(const uint2*)(plr + 64);                                  \
        bp1.u[1] = *(const uint2*)(plr + 72);                                  \
        __builtin_amdgcn_s_setprio(1);                                         \
        _Pragma("unroll")                                                      \
        for (int t = 0; t < 4; ++t) {                                          \
            acc[t] = __builtin_amdgcn_mfma_f32_16x16x32_bf16(av0[t], bp0.v, acc[t], 0, 0, 0); \
            acc[t] = __builtin_amdgcn_mfma_f32_16x16x32_bf16(av1[t], bp1.v, acc[t], 0, 0, 0); \
        }                                                                      \
        __builtin_amdgcn_s_setprio(0);                                         \
        if ((VM) == 2) {                                                       \
            asm volatile("s_waitcnt vmcnt(2)" ::: "memory");                   \
            __builtin_amdgcn_s_barrier();                                      \
        } else if ((VM) == 0) {                                                \
            asm volatile("s_waitcnt vmcnt(0)" ::: "memory");                   \
            __builtin_amdgcn_s_barrier();                                      \
        }                                                                      \
    }

template<int KS>
__global__ __launch_bounds__(512) void attn_kernel(
    const unsigned short* __restrict__ qb, const unsigned short* __restrict__ kb,
    const unsigned short* __restrict__ vtb,
    unsigned short* __restrict__ attnb,
    unsigned short* __restrict__ Opart,    // [KS][NBH][2048][64] bf16 (KS==2)
    float2* __restrict__ mlbuf)            // [KS][NBH][2048]        (KS==2)
{
    const int lane = threadIdx.x & 63;
    const int wv   = threadIdx.x >> 6;
    const int lr   = lane & 15;
    const int lg   = lane >> 4;

    // XCD-aware remap: co-locate the 16 q-tiles of one (bh,ks) group.
    int flat = blockIdx.x + 16 * blockIdx.y + ((KS == 2) ? 384 * blockIdx.z : 0);
    const int xcd = flat & 7;
    const int j   = flat >> 3;
    const int g   = xcd * ((KS == 2) ? 6 : 3) + (j >> 4);
    const int qt  = j & 15;
    const int bh  = (KS == 2) ? (g % 24) : g;
    const int ks  = (KS == 2) ? (g / 24) : 0;
    const int h   = bh % NHEAD, bb = bh / NHEAD;
    const int q0  = qt * 128 + wv * 16;

    __shared__ __align__(16) unsigned short Kt[3][4096];     // 24 KB
    __shared__ __align__(16) unsigned short Vt[3][4096];     // 24 KB
    __shared__ __align__(16) unsigned short PL[8][16][68];   // 17.4 KB, padded

    const char* kbase = (const char*)(kb  + (size_t)bh * S_LEN * DH)
                        + (size_t)ks * (S_LEN / KS) * 128;
    const char* vbase = (const char*)(vtb + (size_t)bh * DH * S_LEN)
                        + (size_t)ks * (S_LEN / KS) * 2;
    const unsigned short* qptr = qb + ((size_t)bh * S_LEN + q0) * DH;

    bf16x8 bq0 = *reinterpret_cast<const bf16x8*>(qptr + (size_t)lr * DH + lg * 8);
    bf16x8 bq1 = *reinterpret_cast<const bf16x8*>(qptr + (size_t)lr * DH + 32 + lg * 8);

    // hoisted addressing ----------------------------------------------------
    const int swr = (lr & 7) << 4;
    const int o0  = (lg * 16) ^ swr;
    const int oD  = (o0 ^ 64) - o0;
    const int L1  = wv * 1024 + lane * 16;
    const int r1  = L1 >> 7;
    const int cb1 = (L1 & 127) ^ ((r1 & 7) << 4);

    const char* kg = kbase + (size_t)r1 * 128 + cb1;
    const char* vg = vbase + (size_t)r1 * 4096 + cb1;
    char* sdK[3] = { (char*)Kt[0] + wv * 1024, (char*)Kt[1] + wv * 1024,
                     (char*)Kt[2] + wv * 1024 };
    char* sdV[3] = { (char*)Vt[0] + wv * 1024, (char*)Vt[1] + wv * 1024,
                     (char*)Vt[2] + wv * 1024 };
    const char* rdK[3] = {
        (const char*)Kt[0] + lr * 128 + o0,
        (const char*)Kt[1] + lr * 128 + o0,
        (const char*)Kt[2] + lr * 128 + o0 };
    const char* rdV[3] = {
        (const char*)Vt[0] + lr * 128 + o0,
        (const char*)Vt[1] + lr * 128 + o0,
        (const char*)Vt[2] + lr * 128 + o0 };
    char* plw = (char*)PL + wv * 2176 + lr * 136;
    const char* plr = plw + lg * 16;

    float m = -1e30f, l = 0.f;
    f32x4 acc[4] = {};
    const float SC = 0.125f * 1.44269504088896f;

    // prologue: stage chunks 0,1 -> bufs 0,1; wait chunk 0 only (vmcnt(2))
    stage16(kg, sdK[0]); kg += 8192;
    stage16(vg, sdV[0]); vg += 128;
    stage16(kg, sdK[1]); kg += 8192;
    stage16(vg, sdV[1]); vg += 128;
    asm volatile("s_waitcnt vmcnt(2)" ::: "memory");
    __builtin_amdgcn_s_barrier();

    if constexpr (KS == 2) {
        for (int it = 0; it < 4; ++it) {       // chunks 0..11 (stage 2..13)
            AC(0, 1, 2); AC(1, 1, 2); AC(2, 1, 2);
        }
        AC(0, 1, 2);                           // c12, stage c14 -> buf 2
        AC(1, 1, 2);                           // c13, stage c15 -> buf 0
        AC(2, 0, 0);                           // c14, drain all
        AC(0, 0, -1);                          // c15, last
    } else {
        for (int it = 0; it < 10; ++it) {      // chunks 0..29 (stage 2..31)
            AC(0, 1, 2); AC(1, 1, 2); AC(2, 1, 2);
        }
        AC(0, 0, 0);                           // c30, drain all
        AC(1, 0, -1);                          // c31, last
    }

    // combine per-lane l across the 4 replicas of each row
    l += __shfl_xor(l, 16);
    l += __shfl_xor(l, 32);

    if constexpr (KS == 1) {
        float rl = 1.0f / l;
        size_t rowbase = ((size_t)(bb * S_LEN + q0 + lr)) * D_MODEL + h * DH;
#pragma unroll
        for (int t = 0; t < 4; ++t) {
            unsigned w0 = pack_bf2(acc[t][0] * rl, acc[t][1] * rl);
            unsigned w1 = pack_bf2(acc[t][2] * rl, acc[t][3] * rl);
            *reinterpret_cast<unsigned*>(attnb + rowbase + t * 16 + lg * 4)     = w0;
            *reinterpret_cast<unsigned*>(attnb + rowbase + t * 16 + lg * 4 + 2) = w1;
        }
    } else {
        size_t base = ((size_t)(ks * NBH + bh) * S_LEN + q0 + lr) * 64;
#pragma unroll
        for (int t = 0; t < 4; ++t) {
            unsigned w0 = pack_bf2(acc[t][0], acc[t][1]);
            unsigned w1 = pack_bf2(acc[t][2], acc[t][3]);
            *reinterpret_cast<unsigned*>(Opart + base + t * 16 + lg * 4)     = w0;
            *reinterpret_cast<unsigned*>(Opart + base + t * 16 + lg * 4 + 2) = w1;
        }
        if (lg == 0)
            mlbuf[(size_t)(ks * NBH + bh) * S_LEN + q0 + lr] = make_float2(m, l);
    }
}

// ---------------------------------------------------------------------------
// Kernel 3b: combine the two K-splits into attnb (bf16 [token][768]).
// ---------------------------------------------------------------------------
__global__ __launch_bounds__(256) void combine_kernel(
    const unsigned short* __restrict__ Opart,
    const float2* __restrict__ mlbuf,
    unsigned short* __restrict__ attnb)
{
    int idx = blockIdx.x * 256 + threadIdx.x;      // 786432 total
    int d4  = idx & 15;
    int h   = (idx >> 4) % 12;
    int tok = idx / 192;
    int bb  = tok >> 11, s = tok & 2047;
    size_t qoff = (size_t)(bb * NHEAD + h) * S_LEN + s;

    float2 ml0 = mlbuf[qoff];
    float2 ml1 = mlbuf[(size_t)NBH * S_LEN + qoff];
    float M  = fmaxf(ml0.x, ml1.x);
    float w0 = __builtin_amdgcn_exp2f(ml0.x - M);
    float w1 = __builtin_amdgcn_exp2f(ml1.x - M);
    float ri = 1.0f / (w0 * ml0.y + w1 * ml1.y);
    w0 *= ri; w1 *= ri;

    size_t ob = qoff * 64 + d4 * 4;
    ushort4 a = *reinterpret_cast<const ushort4*>(Opart + ob);
    ushort4 b = *reinterpret_cast<const ushort4*>(Opart + (size_t)NBH * S_LEN * 64 + ob);
    float o0 = bf2f(a.x) * w0 + bf2f(b.x) * w1;
    float o1 = bf2f(a.y) * w0 + bf2f(b.y) * w1;
    float o2 = bf2f(a.z) * w0 + bf2f(b.z) * w1;
    float o3 = bf2f(a.w) * w0 + bf2f(b.w) * w1;
    uint2 w;
    w.x = pack_bf2(o0, o1);
    w.y = pack_bf2(o2, o3);
    *reinterpret_cast<uint2*>(attnb + (size_t)tok * D_MODEL + h * 64 + d4 * 4) = w;
}

// ---------------------------------------------------------------------------
// Kernel 4: output projection + bias + residual -> fp32 Y.  (128x64 tile)
// XCD swizzle: 384 = 8 xcd * 4 ytiles * 12 xtiles.
// ---------------------------------------------------------------------------
__global__ __launch_bounds__(256) void oproj_kernel(
    const unsigned short* __restrict__ attnb, const unsigned short* __restrict__ Wob,
    const float* __restrict__ bo, const float* __restrict__ Qres,
    float* __restrict__ Y)
{
    const int lane = threadIdx.x & 63;
    const int wv   = threadIdx.x >> 6;
    const int lr   = lane & 15;
    const int lg   = lane >> 4;

    const int flat = blockIdx.x + 12 * blockIdx.y;
    const int xcd  = flat & 7;
    const int j    = flat >> 3;        // [0,48)
    const int ybt  = xcd * 4 + j / 12; // [0,32)
    const int xbt  = j % 12;
    const int row0g = ybt * 128;
    const int col0g = xbt * 64;

    __shared__ __align__(16) unsigned short At[2][128 * 64];
    __shared__ __align__(16) unsigned short Bt[2][64 * 64];

    f32x4 acc[2][4] = {};

    STAGE_TILE(attnb, 1536, row0g, 0, At[0], 4);
    STAGE_TILE(Wob,   1536, col0g, 0, Bt[0], 2);
    __syncthreads();

    for (int s = 0; s < 12; ++s) {
        int cur = s & 1;
        if (s < 11) {
            STAGE_TILE(attnb, 1536, row0g, (s + 1) * 64, At[cur ^ 1], 4);
            STAGE_TILE(Wob,   1536, col0g, (s + 1) * 64, Bt[cur ^ 1], 2);
        }
        bf16x8 a[2][2], b[4][2];
#pragma unroll
        for (int mm = 0; mm < 2; ++mm) {
            int row = wv * 32 + mm * 16 + lr, sw = (row & 7) << 4;
#pragma unroll
            for (int ks = 0; ks < 2; ++ks)
                a[mm][ks] = *reinterpret_cast<const bf16x8*>(
                    (const char*)At[cur] + row * 128 + ((ks * 64 + lg * 16) ^ sw));
        }
#pragma unroll
        for (int n = 0; n < 4; ++n) {
            int row = n * 16 + lr, sw = (row & 7) << 4;
#pragma unroll
            for (int ks = 0; ks < 2; ++ks)
                b[n][ks] = *reinterpret_cast<const bf16x8*>(
                    (const char*)Bt[cur] + row * 128 + ((ks * 64 + lg * 16) ^ sw));
        }
#pragma unroll
        for (int ks = 0; ks < 2; ++ks)
#pragma unroll
            for (int mm = 0; mm < 2; ++mm)
#pragma unroll
                for (int n = 0; n < 4; ++n)
                    acc[mm][n] = __builtin_amdgcn_mfma_f32_16x16x32_bf16(
                        a[mm][ks], b[n][ks], acc[mm][n], 0, 0, 0);
        __syncthreads();
    }

#pragma unroll
    for (int mm = 0; mm < 2; ++mm)
#pragma unroll
        for (int n = 0; n < 4; ++n) {
            int col = col0g + n * 16 + lr;
            float bval = bo[col];
#pragma unroll
            for (int r = 0; r < 4; ++r) {
                int row = row0g + wv * 32 + mm * 16 + lg * 4 + r;
                size_t off = (size_t)row * D_MODEL + col;
                Y[off] = acc[mm][n][r] + bval + Qres[off];
            }
        }
}

// ---------------------------------------------------------------------------
// Kernel 5: LayerNorm per row.
// ---------------------------------------------------------------------------
__global__ __launch_bounds__(256) void ln_kernel(
    const float* __restrict__ Y,
    const float* __restrict__ gamma, const float* __restrict__ beta,
    float* __restrict__ out)
{
    const int lane = threadIdx.x & 63;
    const int row  = blockIdx.x * 4 + (threadIdx.x >> 6);
    const float4* yr = reinterpret_cast<const float4*>(Y + (size_t)row * D_MODEL);

    float4 v[3];
    float sum = 0.f, ss = 0.f;
#pragma unroll
    for (int j = 0; j < 3; ++j) {
        v[j] = yr[lane + 64 * j];
        sum += v[j].x + v[j].y + v[j].z + v[j].w;
        ss  += v[j].x * v[j].x + v[j].y * v[j].y + v[j].z * v[j].z + v[j].w * v[j].w;
    }
#pragma unroll
    for (int msk = 1; msk < 64; msk <<= 1) {
        sum += __shfl_xor(sum, msk);
        ss  += __shfl_xor(ss,  msk);
    }
    float mu  = sum * (1.f / 768.f);
    float var = ss * (1.f / 768.f) - mu * mu;
    float is  = rsqrtf(var + 1e-5f);

    const float4* g4 = reinterpret_cast<const float4*>(gamma);
    const float4* b4 = reinterpret_cast<const float4*>(beta);
    float4* o4 = reinterpret_cast<float4*>(out + (size_t)row * D_MODEL);
#pragma unroll
    for (int j = 0; j < 3; ++j) {
        float4 g = g4[lane + 64 * j], b = b4[lane + 64 * j], r;
        r.x = (v[j].x - mu) * is * g.x + b.x;
        r.y = (v[j].y - mu) * is * g.y + b.y;
        r.z = (v[j].z - mu) * is * g.z + b.z;
        r.w = (v[j].w - mu) * is * g.w + b.w;
        o4[lane + 64 * j] = r;
    }
}

// ---------------------------------------------------------------------------
extern "C" void kernel_launch(void* const* d_in, const int* in_sizes, int n_in,
                              void* d_out, int out_size, void* d_ws, size_t ws_size,
                              hipStream_t stream)
{
    const float* Q     = (const float*)d_in[0];
    const float* Wq    = (const float*)d_in[1];
    const float* bq    = (const float*)d_in[2];
    const float* Wk    = (const float*)d_in[3];
    const float* bk    = (const float*)d_in[4];
    const float* Wv    = (const float*)d_in[5];
    const float* bv    = (const float*)d_in[6];
    const float* Wo    = (const float*)d_in[7];
    const float* bo    = (const float*)d_in[8];
    const float* gamma = (const float*)d_in[9];
    const float* beta  = (const float*)d_in[10];
    float* out = (float*)d_out;

    char* ws = (char*)d_ws;
    unsigned short* Xb    = (unsigned short*)(ws + 0);
    unsigned short* Wqb   = (unsigned short*)(ws + 6291456);    // Wq,Wk,Wv contiguous
    unsigned short* Wkb   = (unsigned short*)(ws + 7471104);
    unsigned short* Wvb   = (unsigned short*)(ws + 8650752);
    unsigned short* Wob   = (unsigned short*)(ws + 9830400);
    unsigned short* qb    = (unsigned short*)(ws + 11010048);
    unsigned short* kb    = (unsigned short*)(ws + 17301504);
    unsigned short* vtb   = (unsigned short*)(ws + 23592960);
    unsigned short* attnb = (unsigned short*)(ws + 29884416);
    float*          Yf    = (float*)        (ws + 36175872);    // 12.6 MB
    unsigned short* Opartb = (unsigned short*)(ws + 36175872);  // overlay
    float2*         mlbuf  = (float2*)       (ws + 61341696);

    const bool splitk = (ws_size >= 62128128ull);

    convert_kernel<<<5376, 256, 0, stream>>>(Q, Wq, Wk, Wv, Wo, Xb, Wqb, Wkb, Wvb, Wob);
    qkv_gemm_kernel<<<dim3(18, 32), 256, 0, stream>>>(Xb, Wqb, bq, bk, bv, qb, kb, vtb);
    if (splitk) {
        attn_kernel<2><<<dim3(16, 24, 2), 512, 0, stream>>>(qb, kb, vtb, attnb,
                                                            Opartb, mlbuf);
        combine_kernel<<<3072, 256, 0, stream>>>(Opartb, mlbuf, attnb);
    } else {
        attn_kernel<1><<<dim3(16, 24), 512, 0, stream>>>(qb, kb, vtb, attnb,
                                                         Opartb, mlbuf);
    }
    oproj_kernel<<<dim3(12, 32), 256, 0, stream>>>(attnb, Wob, bo, Q, Yf);
    ln_kernel<<<1024, 256, 0, stream>>>(Yf, gamma, beta, out);
}

// Round 16
// 109.756 us; speedup vs baseline: 1.1004x; 1.0077x over previous
//
#include <hip/hip_runtime.h>
#include <hip/hip_bf16.h>

#define D_MODEL 768
#define S_LEN   2048
#define BATCH   2
#define NHEAD   12
#define DH      64
#define NTOK    (BATCH * S_LEN)   // 4096
#define NBH     (BATCH * NHEAD)   // 24

typedef __attribute__((ext_vector_type(8))) short bf16x8;   // 8 bf16 in 4 VGPRs
typedef __attribute__((ext_vector_type(4))) float f32x4;

__device__ inline unsigned short f2bf(float f) {
    union { float f; unsigned u; } v; v.f = f;
    unsigned u = v.u;
    u += 0x7fffu + ((u >> 16) & 1u);
    return (unsigned short)(u >> 16);
}

__device__ inline unsigned pack_bf2(float a, float b) {
    union { __hip_bfloat162 h2; unsigned u; } cv;
    cv.h2 = __float22bfloat162_rn(make_float2(a, b));   // v_cvt_pk_bf16_f32
    return cv.u;
}

__device__ inline float bf2f(unsigned short u) {
    union { unsigned u; float f; } c; c.u = ((unsigned)u) << 16; return c.f;
}

// async global->LDS, 16B per lane. LDS dest is wave-uniform base (+lane*16 by HW).
__device__ inline void stage16(const void* g, void* l) {
    __builtin_amdgcn_global_load_lds(
        (const __attribute__((address_space(1))) unsigned*)g,
        (__attribute__((address_space(3))) unsigned*)l, 16, 0, 0);
}

// ---------------------------------------------------------------------------
// Kernel 1: fp32 -> bf16 conversion of X and the 4 weight matrices
// ---------------------------------------------------------------------------
__global__ __launch_bounds__(256) void convert_kernel(
    const float* __restrict__ Q,
    const float* __restrict__ Wq, const float* __restrict__ Wk,
    const float* __restrict__ Wv, const float* __restrict__ Wo,
    unsigned short* __restrict__ Xb,
    unsigned short* __restrict__ Wqb, unsigned short* __restrict__ Wkb,
    unsigned short* __restrict__ Wvb, unsigned short* __restrict__ Wob)
{
    const int XV = NTOK * D_MODEL / 4;
    const int WV = D_MODEL * D_MODEL / 4;
    int idx = blockIdx.x * 256 + threadIdx.x;
    if (idx >= XV + 4 * WV) return;

    const float* src; unsigned short* dst; int off;
    if (idx < XV) { src = Q; dst = Xb; off = idx; }
    else {
        int i2 = idx - XV;
        int seg = i2 / WV; off = i2 - seg * WV;
        if      (seg == 0) { src = Wq; dst = Wqb; }
        else if (seg == 1) { src = Wk; dst = Wkb; }
        else if (seg == 2) { src = Wv; dst = Wvb; }
        else               { src = Wo; dst = Wob; }
    }
    float4 v = reinterpret_cast<const float4*>(src)[off];
    uint2 o;
    o.x = pack_bf2(v.x, v.y);
    o.y = pack_bf2(v.z, v.w);
    reinterpret_cast<uint2*>(dst)[off] = o;
}

// ===========================================================================
// Staged GEMM pieces, XOR-swizzled LDS via pre-swizzled global source.
// ===========================================================================
#define STAGE_TILE(glob, rowstrideB, row0, k0, ldsbase, nIss)                 \
    _Pragma("unroll")                                                          \
    for (int i = 0; i < (nIss); ++i) {                                         \
        int L = i * 4096 + wv * 1024 + lane * 16;                              \
        int row = L >> 7;                                                      \
        int colb = (L & 127) ^ ((row & 7) << 4);                               \
        stage16((const char*)(glob) + (size_t)((row0) + row) * (rowstrideB)    \
                    + ((k0) << 1) + colb,                                      \
                (char*)(ldsbase) + i * 4096 + wv * 1024);                      \
    }

// ---------------------------------------------------------------------------
// Kernel 2: fused QKV projection, 128x128 tile.  B = [Wq;Wk;Wv] (N=2304).
// XCD swizzle: the 4-row-tile group sharing an X panel co-locates per XCD.
// ---------------------------------------------------------------------------
__global__ __launch_bounds__(256) void qkv_gemm_kernel(
    const unsigned short* __restrict__ Xb,
    const unsigned short* __restrict__ Wall,   // [2304][768]
    const float* __restrict__ bq, const float* __restrict__ bk,
    const float* __restrict__ bv,
    unsigned short* __restrict__ qb, unsigned short* __restrict__ kb,
    unsigned short* __restrict__ vtb)
{
    const int lane = threadIdx.x & 63;
    const int wv   = threadIdx.x >> 6;
    const int lr   = lane & 15;
    const int lg   = lane >> 4;
    const int wr   = wv >> 1;          // 2x2 wave grid
    const int wc   = wv & 1;

    // XCD-aware remap: 576 = 8 xcd * 4 ytiles * 18 xtiles
    const int flat = blockIdx.x + 18 * blockIdx.y;
    const int xcd  = flat & 7;
    const int j    = flat >> 3;        // [0,72)
    const int ybt  = xcd * 4 + j / 18; // row tile [0,32)
    const int xbt  = j % 18;           // col tile [0,18)
    const int row0g = ybt * 128;
    const int col0g = xbt * 128;

    __shared__ __align__(16) unsigned short At[2][128 * 64];   // 16 KB each
    __shared__ __align__(16) unsigned short Bt[2][128 * 64];

    f32x4 acc[4][4] = {};

    STAGE_TILE(Xb,   1536, row0g, 0, At[0], 4);
    STAGE_TILE(Wall, 1536, col0g, 0, Bt[0], 4);
    __syncthreads();

    for (int s = 0; s < 12; ++s) {
        int cur = s & 1;
        if (s < 11) {
            STAGE_TILE(Xb,   1536, row0g, (s + 1) * 64, At[cur ^ 1], 4);
            STAGE_TILE(Wall, 1536, col0g, (s + 1) * 64, Bt[cur ^ 1], 4);
        }
        bf16x8 a[4][2], b[4][2];
#pragma unroll
        for (int mm = 0; mm < 4; ++mm) {
            int row = wr * 64 + mm * 16 + lr, sw = (row & 7) << 4;
#pragma unroll
            for (int ks = 0; ks < 2; ++ks)
                a[mm][ks] = *reinterpret_cast<const bf16x8*>(
                    (const char*)At[cur] + row * 128 + ((ks * 64 + lg * 16) ^ sw));
        }
#pragma unroll
        for (int n = 0; n < 4; ++n) {
            int row = wc * 64 + n * 16 + lr, sw = (row & 7) << 4;
#pragma unroll
            for (int ks = 0; ks < 2; ++ks)
                b[n][ks] = *reinterpret_cast<const bf16x8*>(
                    (const char*)Bt[cur] + row * 128 + ((ks * 64 + lg * 16) ^ sw));
        }
#pragma unroll
        for (int ks = 0; ks < 2; ++ks)
#pragma unroll
            for (int mm = 0; mm < 4; ++mm)
#pragma unroll
                for (int n = 0; n < 4; ++n)
                    acc[mm][n] = __builtin_amdgcn_mfma_f32_16x16x32_bf16(
                        a[mm][ks], b[n][ks], acc[mm][n], 0, 0, 0);
        __syncthreads();
    }

    const int which   = xbt / 6;                  // 2304/128=18, 6 per output
    const int colbase = (xbt % 6) * 128;
    const float* bias = (which == 0) ? bq : (which == 1) ? bk : bv;
#pragma unroll
    for (int mm = 0; mm < 4; ++mm) {
#pragma unroll
        for (int n = 0; n < 4; ++n) {
            int col = colbase + wc * 64 + n * 16 + lr;
            float bval = bias[col];
            int h = col >> 6, d = col & 63;
            int rowg = row0g + wr * 64 + mm * 16 + lg * 4;
            int bb = rowg >> 11, s0 = rowg & 2047;
            if (which == 2) {
                uint2 w;
                w.x = pack_bf2(acc[mm][n][0] + bval, acc[mm][n][1] + bval);
                w.y = pack_bf2(acc[mm][n][2] + bval, acc[mm][n][3] + bval);
                *reinterpret_cast<uint2*>(
                    vtb + ((size_t)(bb * NHEAD + h) * DH + d) * S_LEN + s0) = w;
            } else {
                unsigned short* dst = (which == 0) ? qb : kb;
#pragma unroll
                for (int r = 0; r < 4; ++r)
                    dst[((size_t)(bb * NHEAD + h) * S_LEN + s0 + r) * DH + d] =
                        f2bf(acc[mm][n][r] + bval);
            }
        }
    }
}

// ---------------------------------------------------------------------------
// Kernel 3: attention.  8 waves x 16 q-rows; K,V triple-buffered LDS,
// counted vmcnt(2), depth-2 prefetch.  XCD swizzle: the 16 q-blocks sharing
// one (bh,ks) K/V co-locate on one XCD.
// ---------------------------------------------------------------------------
#define AC(BUF, DOSTAGE, VM)                                                   \
    {                                                                          \
        if (DOSTAGE) {                                                         \
            stage16(kg, sdK[((BUF) + 2) % 3]); kg += 8192;                     \
            stage16(vg, sdV[((BUF) + 2) % 3]); vg += 128;                      \
        }                                                                      \
        f32x4 s[4] = {};                                                       \
        __builtin_amdgcn_s_setprio(1);                                         \
        _Pragma("unroll")                                                      \
        for (int kt = 0; kt < 4; ++kt) {                                       \
            bf16x8 ak0 = *(const bf16x8*)(rdK[BUF] + kt * 2048);               \
            bf16x8 ak1 = *(const bf16x8*)(rdK[BUF] + kt * 2048 + oD);          \
            s[kt] = __builtin_amdgcn_mfma_f32_16x16x32_bf16(ak0, bq0, s[kt], 0, 0, 0); \
            s[kt] = __builtin_amdgcn_mfma_f32_16x16x32_bf16(ak1, bq1, s[kt], 0, 0, 0); \
        }                                                                      \
        __builtin_amdgcn_s_setprio(0);                                         \
        bf16x8 av0[4], av1[4];                                                 \
        _Pragma("unroll")                                                      \
        for (int t = 0; t < 4; ++t) {                                          \
            av0[t] = *(const bf16x8*)(rdV[BUF] + t * 2048);                    \
            av1[t] = *(const bf16x8*)(rdV[BUF] + t * 2048 + oD);               \
        }                                                                      \
        float g0 = fmaxf(fmaxf(s[0][0], s[0][1]), s[0][2]);                    \
        float g1 = fmaxf(fmaxf(s[0][3], s[1][0]), s[1][1]);                    \
        float g2 = fmaxf(fmaxf(s[1][2], s[1][3]), s[2][0]);                    \
        float g3 = fmaxf(fmaxf(s[2][1], s[2][2]), s[2][3]);                    \
        float g4 = fmaxf(fmaxf(s[3][0], s[3][1]), s[3][2]);                    \
        float mx = fmaxf(fmaxf(fmaxf(g0, g1), g2), fmaxf(fmaxf(g3, g4), s[3][3])); \
        if (__any(mx * SC > m + 8.0f)) {                                       \
            float mg = mx * SC;                                                \
            mg = fmaxf(mg, __shfl_xor(mg, 16));                                \
            mg = fmaxf(mg, __shfl_xor(mg, 32));                                \
            float mn = fmaxf(m, mg);                                           \
            float sf = __builtin_amdgcn_exp2f(m - mn);                         \
            m = mn; l *= sf;                                                   \
            _Pragma("unroll")                                                  \
            for (int t = 0; t < 4; ++t) acc[t] *= sf;                          \
        }                                                                      \
        float p[16];                                                           \
        _Pragma("unroll")                                                      \
        for (int kt = 0; kt < 4; ++kt)                                         \
            _Pragma("unroll")                                                  \
            for (int r = 0; r < 4; ++r)                                        \
                p[kt * 4 + r] = __builtin_amdgcn_exp2f(fmaf(s[kt][r], SC, -m)); \
        float sum = ((p[0] + p[1]) + (p[2] + p[3])) + ((p[4] + p[5]) + (p[6] + p[7])); \
        sum += ((p[8] + p[9]) + (p[10] + p[11])) + ((p[12] + p[13]) + (p[14] + p[15])); \
        l += sum;                                                              \
        _Pragma("unroll")                                                      \
        for (int kt = 0; kt < 4; ++kt) {                                       \
            uint2 w;                                                           \
            w.x = pack_bf2(p[kt * 4 + 0], p[kt * 4 + 1]);                      \
            w.y = pack_bf2(p[kt * 4 + 2], p[kt * 4 + 3]);                      \
            *(uint2*)(plw + kt * 32 + lg * 8) = w;                             \
        }                                                                      \
        union { bf16x8 v; uint2 u[2]; } bp0, bp1;                              \
        bp0.u[0] = *(const uint2*)(plr);                                       \
        bp0.u[1] = *(const uint2*)(plr + 8);                                   \
        bp1.u[0] = *(const uint2*)(plr + 64);                                  \
        bp1.u[1] = *(const uint2*)(plr + 72);                                  \
        __builtin_amdgcn_s_setprio(1);                                         \
        _Pragma("unroll")                                                      \
        for (int t = 0; t < 4; ++t) {                                          \
            acc[t] = __builtin_amdgcn_mfma_f32_16x16x32_bf16(av0[t], bp0.v, acc[t], 0, 0, 0); \
            acc[t] = __builtin_amdgcn_mfma_f32_16x16x32_bf16(av1[t], bp1.v, acc[t], 0, 0, 0); \
        }                                                                      \
        __builtin_amdgcn_s_setprio(0);                                         \
        if ((VM) == 2) {                                                       \
            asm volatile("s_waitcnt vmcnt(2)" ::: "memory");                   \
            __builtin_amdgcn_s_barrier();                                      \
        } else if ((VM) == 0) {                                                \
            asm volatile("s_waitcnt vmcnt(0)" ::: "memory");                   \
            __builtin_amdgcn_s_barrier();                                      \
        }                                                                      \
    }

template<int KS>
__global__ __launch_bounds__(512) void attn_kernel(
    const unsigned short* __restrict__ qb, const unsigned short* __restrict__ kb,
    const unsigned short* __restrict__ vtb,
    unsigned short* __restrict__ attnb,
    unsigned short* __restrict__ Opart,    // [KS][NBH][2048][64] bf16 (KS==2)
    float2* __restrict__ mlbuf)            // [KS][NBH][2048]        (KS==2)
{
    const int lane = threadIdx.x & 63;
    const int wv   = threadIdx.x >> 6;
    const int lr   = lane & 15;
    const int lg   = lane >> 4;

    // XCD-aware remap: co-locate the 16 q-tiles of one (bh,ks) group.
    int flat = blockIdx.x + 16 * blockIdx.y + ((KS == 2) ? 384 * blockIdx.z : 0);
    const int xcd = flat & 7;
    const int j   = flat >> 3;
    const int g   = xcd * ((KS == 2) ? 6 : 3) + (j >> 4);
    const int qt  = j & 15;
    const int bh  = (KS == 2) ? (g % 24) : g;
    const int ks  = (KS == 2) ? (g / 24) : 0;
    const int h   = bh % NHEAD, bb = bh / NHEAD;
    const int q0  = qt * 128 + wv * 16;

    __shared__ __align__(16) unsigned short Kt[3][4096];     // 24 KB
    __shared__ __align__(16) unsigned short Vt[3][4096];     // 24 KB
    __shared__ __align__(16) unsigned short PL[8][16][68];   // 17.4 KB, padded

    const char* kbase = (const char*)(kb  + (size_t)bh * S_LEN * DH)
                        + (size_t)ks * (S_LEN / KS) * 128;
    const char* vbase = (const char*)(vtb + (size_t)bh * DH * S_LEN)
                        + (size_t)ks * (S_LEN / KS) * 2;
    const unsigned short* qptr = qb + ((size_t)bh * S_LEN + q0) * DH;

    bf16x8 bq0 = *reinterpret_cast<const bf16x8*>(qptr + (size_t)lr * DH + lg * 8);
    bf16x8 bq1 = *reinterpret_cast<const bf16x8*>(qptr + (size_t)lr * DH + 32 + lg * 8);

    // hoisted addressing ----------------------------------------------------
    const int swr = (lr & 7) << 4;
    const int o0  = (lg * 16) ^ swr;
    const int oD  = (o0 ^ 64) - o0;
    const int L1  = wv * 1024 + lane * 16;
    const int r1  = L1 >> 7;
    const int cb1 = (L1 & 127) ^ ((r1 & 7) << 4);

    const char* kg = kbase + (size_t)r1 * 128 + cb1;
    const char* vg = vbase + (size_t)r1 * 4096 + cb1;
    char* sdK[3] = { (char*)Kt[0] + wv * 1024, (char*)Kt[1] + wv * 1024,
                     (char*)Kt[2] + wv * 1024 };
    char* sdV[3] = { (char*)Vt[0] + wv * 1024, (char*)Vt[1] + wv * 1024,
                     (char*)Vt[2] + wv * 1024 };
    const char* rdK[3] = {
        (const char*)Kt[0] + lr * 128 + o0,
        (const char*)Kt[1] + lr * 128 + o0,
        (const char*)Kt[2] + lr * 128 + o0 };
    const char* rdV[3] = {
        (const char*)Vt[0] + lr * 128 + o0,
        (const char*)Vt[1] + lr * 128 + o0,
        (const char*)Vt[2] + lr * 128 + o0 };
    char* plw = (char*)PL + wv * 2176 + lr * 136;
    const char* plr = plw + lg * 16;

    float m = -1e30f, l = 0.f;
    f32x4 acc[4] = {};
    const float SC = 0.125f * 1.44269504088896f;

    // prologue: stage chunks 0,1 -> bufs 0,1; wait chunk 0 only (vmcnt(2))
    stage16(kg, sdK[0]); kg += 8192;
    stage16(vg, sdV[0]); vg += 128;
    stage16(kg, sdK[1]); kg += 8192;
    stage16(vg, sdV[1]); vg += 128;
    asm volatile("s_waitcnt vmcnt(2)" ::: "memory");
    __builtin_amdgcn_s_barrier();

    if constexpr (KS == 2) {
        for (int it = 0; it < 4; ++it) {       // chunks 0..11 (stage 2..13)
            AC(0, 1, 2); AC(1, 1, 2); AC(2, 1, 2);
        }
        AC(0, 1, 2);                           // c12, stage c14 -> buf 2
        AC(1, 1, 2);                           // c13, stage c15 -> buf 0
        AC(2, 0, 0);                           // c14, drain all
        AC(0, 0, -1);                          // c15, last
    } else {
        for (int it = 0; it < 10; ++it) {      // chunks 0..29 (stage 2..31)
            AC(0, 1, 2); AC(1, 1, 2); AC(2, 1, 2);
        }
        AC(0, 0, 0);                           // c30, drain all
        AC(1, 0, -1);                          // c31, last
    }

    // combine per-lane l across the 4 replicas of each row
    l += __shfl_xor(l, 16);
    l += __shfl_xor(l, 32);

    if constexpr (KS == 1) {
        float rl = 1.0f / l;
        size_t rowbase = ((size_t)(bb * S_LEN + q0 + lr)) * D_MODEL + h * DH;
#pragma unroll
        for (int t = 0; t < 4; ++t) {
            unsigned w0 = pack_bf2(acc[t][0] * rl, acc[t][1] * rl);
            unsigned w1 = pack_bf2(acc[t][2] * rl, acc[t][3] * rl);
            *reinterpret_cast<unsigned*>(attnb + rowbase + t * 16 + lg * 4)     = w0;
            *reinterpret_cast<unsigned*>(attnb + rowbase + t * 16 + lg * 4 + 2) = w1;
        }
    } else {
        size_t base = ((size_t)(ks * NBH + bh) * S_LEN + q0 + lr) * 64;
#pragma unroll
        for (int t = 0; t < 4; ++t) {
            unsigned w0 = pack_bf2(acc[t][0], acc[t][1]);
            unsigned w1 = pack_bf2(acc[t][2], acc[t][3]);
            *reinterpret_cast<unsigned*>(Opart + base + t * 16 + lg * 4)     = w0;
            *reinterpret_cast<unsigned*>(Opart + base + t * 16 + lg * 4 + 2) = w1;
        }
        if (lg == 0)
            mlbuf[(size_t)(ks * NBH + bh) * S_LEN + q0 + lr] = make_float2(m, l);
    }
}

// ---------------------------------------------------------------------------
// Kernel 3b: combine the two K-splits into attnb (bf16 [token][768]).
// ---------------------------------------------------------------------------
__global__ __launch_bounds__(256) void combine_kernel(
    const unsigned short* __restrict__ Opart,
    const float2* __restrict__ mlbuf,
    unsigned short* __restrict__ attnb)
{
    int idx = blockIdx.x * 256 + threadIdx.x;      // 786432 total
    int d4  = idx & 15;
    int h   = (idx >> 4) % 12;
    int tok = idx / 192;
    int bb  = tok >> 11, s = tok & 2047;
    size_t qoff = (size_t)(bb * NHEAD + h) * S_LEN + s;

    float2 ml0 = mlbuf[qoff];
    float2 ml1 = mlbuf[(size_t)NBH * S_LEN + qoff];
    float M  = fmaxf(ml0.x, ml1.x);
    float w0 = __builtin_amdgcn_exp2f(ml0.x - M);
    float w1 = __builtin_amdgcn_exp2f(ml1.x - M);
    float ri = 1.0f / (w0 * ml0.y + w1 * ml1.y);
    w0 *= ri; w1 *= ri;

    size_t ob = qoff * 64 + d4 * 4;
    ushort4 a = *reinterpret_cast<const ushort4*>(Opart + ob);
    ushort4 b = *reinterpret_cast<const ushort4*>(Opart + (size_t)NBH * S_LEN * 64 + ob);
    float o0 = bf2f(a.x) * w0 + bf2f(b.x) * w1;
    float o1 = bf2f(a.y) * w0 + bf2f(b.y) * w1;
    float o2 = bf2f(a.z) * w0 + bf2f(b.z) * w1;
    float o3 = bf2f(a.w) * w0 + bf2f(b.w) * w1;
    uint2 w;
    w.x = pack_bf2(o0, o1);
    w.y = pack_bf2(o2, o3);
    *reinterpret_cast<uint2*>(attnb + (size_t)tok * D_MODEL + h * 64 + d4 * 4) = w;
}

// ---------------------------------------------------------------------------
// Kernel 4: output projection + bias + residual -> fp32 Y.  (128x64 tile)
// XCD swizzle: 384 = 8 xcd * 4 ytiles * 12 xtiles.
// ---------------------------------------------------------------------------
__global__ __launch_bounds__(256) void oproj_kernel(
    const unsigned short* __restrict__ attnb, const unsigned short* __restrict__ Wob,
    const float* __restrict__ bo, const float* __restrict__ Qres,
    float* __restrict__ Y)
{
    const int lane = threadIdx.x & 63;
    const int wv   = threadIdx.x >> 6;
    const int lr   = lane & 15;
    const int lg   = lane >> 4;

    const int flat = blockIdx.x + 12 * blockIdx.y;
    const int xcd  = flat & 7;
    const int j    = flat >> 3;        // [0,48)
    const int ybt  = xcd * 4 + j / 12; // [0,32)
    const int xbt  = j % 12;
    const int row0g = ybt * 128;
    const int col0g = xbt * 64;

    __shared__ __align__(16) unsigned short At[2][128 * 64];
    __shared__ __align__(16) unsigned short Bt[2][64 * 64];

    f32x4 acc[2][4] = {};

    STAGE_TILE(attnb, 1536, row0g, 0, At[0], 4);
    STAGE_TILE(Wob,   1536, col0g, 0, Bt[0], 2);
    __syncthreads();

    for (int s = 0; s < 12; ++s) {
        int cur = s & 1;
        if (s < 11) {
            STAGE_TILE(attnb, 1536, row0g, (s + 1) * 64, At[cur ^ 1], 4);
            STAGE_TILE(Wob,   1536, col0g, (s + 1) * 64, Bt[cur ^ 1], 2);
        }
        bf16x8 a[2][2], b[4][2];
#pragma unroll
        for (int mm = 0; mm < 2; ++mm) {
            int row = wv * 32 + mm * 16 + lr, sw = (row & 7) << 4;
#pragma unroll
            for (int ks = 0; ks < 2; ++ks)
                a[mm][ks] = *reinterpret_cast<const bf16x8*>(
                    (const char*)At[cur] + row * 128 + ((ks * 64 + lg * 16) ^ sw));
        }
#pragma unroll
        for (int n = 0; n < 4; ++n) {
            int row = n * 16 + lr, sw = (row & 7) << 4;
#pragma unroll
            for (int ks = 0; ks < 2; ++ks)
                b[n][ks] = *reinterpret_cast<const bf16x8*>(
                    (const char*)Bt[cur] + row * 128 + ((ks * 64 + lg * 16) ^ sw));
        }
#pragma unroll
        for (int ks = 0; ks < 2; ++ks)
#pragma unroll
            for (int mm = 0; mm < 2; ++mm)
#pragma unroll
                for (int n = 0; n < 4; ++n)
                    acc[mm][n] = __builtin_amdgcn_mfma_f32_16x16x32_bf16(
                        a[mm][ks], b[n][ks], acc[mm][n], 0, 0, 0);
        __syncthreads();
    }

#pragma unroll
    for (int mm = 0; mm < 2; ++mm)
#pragma unroll
        for (int n = 0; n < 4; ++n) {
            int col = col0g + n * 16 + lr;
            float bval = bo[col];
#pragma unroll
            for (int r = 0; r < 4; ++r) {
                int row = row0g + wv * 32 + mm * 16 + lg * 4 + r;
                size_t off = (size_t)row * D_MODEL + col;
                Y[off] = acc[mm][n][r] + bval + Qres[off];
            }
        }
}

// ---------------------------------------------------------------------------
// Kernel 5: LayerNorm per row.
// ---------------------------------------------------------------------------
__global__ __launch_bounds__(256) void ln_kernel(
    const float* __restrict__ Y,
    const float* __restrict__ gamma, const float* __restrict__ beta,
    float* __restrict__ out)
{
    const int lane = threadIdx.x & 63;
    const int row  = blockIdx.x * 4 + (threadIdx.x >> 6);
    const float4* yr = reinterpret_cast<const float4*>(Y + (size_t)row * D_MODEL);

    float4 v[3];
    float sum = 0.f, ss = 0.f;
#pragma unroll
    for (int j = 0; j < 3; ++j) {
        v[j] = yr[lane + 64 * j];
        sum += v[j].x + v[j].y + v[j].z + v[j].w;
        ss  += v[j].x * v[j].x + v[j].y * v[j].y + v[j].z * v[j].z + v[j].w * v[j].w;
    }
#pragma unroll
    for (int msk = 1; msk < 64; msk <<= 1) {
        sum += __shfl_xor(sum, msk);
        ss  += __shfl_xor(ss,  msk);
    }
    float mu  = sum * (1.f / 768.f);
    float var = ss * (1.f / 768.f) - mu * mu;
    float is  = rsqrtf(var + 1e-5f);

    const float4* g4 = reinterpret_cast<const float4*>(gamma);
    const float4* b4 = reinterpret_cast<const float4*>(beta);
    float4* o4 = reinterpret_cast<float4*>(out + (size_t)row * D_MODEL);
#pragma unroll
    for (int j = 0; j < 3; ++j) {
        float4 g = g4[lane + 64 * j], b = b4[lane + 64 * j], r;
        r.x = (v[j].x - mu) * is * g.x + b.x;
        r.y = (v[j].y - mu) * is * g.y + b.y;
        r.z = (v[j].z - mu) * is * g.z + b.z;
        r.w = (v[j].w - mu) * is * g.w + b.w;
        o4[lane + 64 * j] = r;
    }
}

// ---------------------------------------------------------------------------
extern "C" void kernel_launch(void* const* d_in, const int* in_sizes, int n_in,
                              void* d_out, int out_size, void* d_ws, size_t ws_size,
                              hipStream_t stream)
{
    const float* Q     = (const float*)d_in[0];
    const float* Wq    = (const float*)d_in[1];
    const float* bq    = (const float*)d_in[2];
    const float* Wk    = (const float*)d_in[3];
    const float* bk    = (const float*)d_in[4];
    const float* Wv    = (const float*)d_in[5];
    const float* bv    = (const float*)d_in[6];
    const float* Wo    = (const float*)d_in[7];
    const float* bo    = (const float*)d_in[8];
    const float* gamma = (const float*)d_in[9];
    const float* beta  = (const float*)d_in[10];
    float* out = (float*)d_out;

    char* ws = (char*)d_ws;
    unsigned short* Xb    = (unsigned short*)(ws + 0);
    unsigned short* Wqb   = (unsigned short*)(ws + 6291456);    // Wq,Wk,Wv contiguous
    unsigned short* Wkb   = (unsigned short*)(ws + 7471104);
    unsigned short* Wvb   = (unsigned short*)(ws + 8650752);
    unsigned short* Wob   = (unsigned short*)(ws + 9830400);
    unsigned short* qb    = (unsigned short*)(ws + 11010048);
    unsigned short* kb    = (unsigned short*)(ws + 17301504);
    unsigned short* vtb   = (unsigned short*)(ws + 23592960);
    unsigned short* attnb = (unsigned short*)(ws + 29884416);
    float*          Yf    = (float*)        (ws + 36175872);    // 12.6 MB
    unsigned short* Opartb = (unsigned short*)(ws + 36175872);  // overlay
    float2*         mlbuf  = (float2*)       (ws + 61341696);

    const bool splitk = (ws_size >= 62128128ull);

    convert_kernel<<<5376, 256, 0, stream>>>(Q, Wq, Wk, Wv, Wo, Xb, Wqb, Wkb, Wvb, Wob);
    qkv_gemm_kernel<<<dim3(18, 32), 256, 0, stream>>>(Xb, Wqb, bq, bk, bv, qb, kb, vtb);
    if (splitk) {
        attn_kernel<2><<<dim3(16, 24, 2), 512, 0, stream>>>(qb, kb, vtb, attnb,
                                                            Opartb, mlbuf);
        combine_kernel<<<3072, 256, 0, stream>>>(Opartb, mlbuf, attnb);
    } else {
        attn_kernel<1><<<dim3(16, 24), 512, 0, stream>>>(qb, kb, vtb, attnb,
                                                         Opartb, mlbuf);
    }
    oproj_kernel<<<dim3(12, 32), 256, 0, stream>>>(attnb, Wob, bo, Q, Yf);
    ln_kernel<<<1024, 256, 0, stream>>>(Yf, gamma, beta, out);
}